// Round 11
// baseline (102.638 us; speedup 1.0000x reference)
//
#include <hip/hip_runtime.h>
#include <stdint.h>

#define BS 256
#define CPB 4          // chunks (of BS rows) per count/sel block

typedef unsigned long long u64;
typedef float f32x4 __attribute__((ext_vector_type(4)));

// ---------------- Node 1: per-(segment,slot) partial min + zero ws_total ----
__global__ __launch_bounds__(BS)
void k_segmin(const float* __restrict__ score, const int* __restrict__ track,
              const int* __restrict__ rs, int B, int SPS,
              float* __restrict__ part_min, int* __restrict__ ws_total) {
    int b = blockIdx.x;
    if (b == 0 && threadIdx.x == 0) *ws_total = 0;
    int s = b / SPS, j = b - s * SPS;
    int r0 = rs[s], r1 = rs[s + 1];
    int len = r1 - r0;
    int per = (len + SPS - 1) / SPS;
    int a = r0 + j * per;
    int e = min(r1, a + per);
    float m = INFINITY;
    for (int i = a + (int)threadIdx.x; i < e; i += BS)
        m = fminf(m, track[i] ? 0.0f : score[i]);
    for (int d = 32; d > 0; d >>= 1) m = fminf(m, __shfl_down(m, d));
    __shared__ float wmin[BS / 64];
    if ((threadIdx.x & 63) == 0) wmin[threadIdx.x >> 6] = m;
    __syncthreads();
    if (threadIdx.x == 0) {
        float mm = wmin[0];
        for (int k = 1; k < BS / 64; ++k) mm = fminf(mm, wmin[k]);
        part_min[b] = mm;
    }
}

// ---------------- Node 2: threshold + ballots -> masks + counts + total -----
__global__ __launch_bounds__(BS)
void k_count(const float* __restrict__ score, const int* __restrict__ track,
             const float* __restrict__ part_min, int N, int B, int SPS,
             u64* __restrict__ gmask, int* __restrict__ cnts,
             int* __restrict__ ws_total) {
    const int b = blockIdx.x, tid = threadIdx.x;
    const int w = tid >> 6, lane = tid & 63;
    __shared__ float shT;
    __shared__ u64 smask[CPB * 4];

    if (tid < 64) {
        float m = -INFINITY;
        for (int s = tid; s < B; s += 64) {
            float mn = INFINITY;
            for (int j = 0; j < SPS; ++j) mn = fminf(mn, part_min[s * SPS + j]);
            m = fmaxf(m, mn);
        }
        for (int d = 32; d > 0; d >>= 1) m = fmaxf(m, __shfl_xor(m, d));
        if (tid == 0) shT = (m < 0.1f) ? 0.1f : (m + 1e-7f);
    }
    __syncthreads();
    const float T = shT;

    const long Rb = (long)b * CPB * BS;
    for (int c = 0; c < CPB; ++c) {
        long i = Rb + (long)c * BS + tid;
        bool pred = (i < N) && ((track[i] ? 0.0f : score[i]) <= T);
        u64 bal = __ballot(pred);
        if (lane == 0) smask[c * 4 + w] = bal;
    }
    __syncthreads();
    if (tid < CPB * 4) gmask[(long)b * CPB * 4 + tid] = smask[tid];
    if (tid == 0) {
        int c = 0;
        for (int k = 0; k < CPB * 4; ++k) c += __popcll(smask[k]);
        cnts[b] = c;
        atomicAdd(ws_total, c);
    }
}

// ---------------- Node 3: selected-row index list (floats) + new_rs ---------
__global__ __launch_bounds__(BS)
void k_sel(const int* __restrict__ rsp, const u64* __restrict__ gmask,
           const int* __restrict__ cnts, int N, int B, int G2,
           float* __restrict__ out_idx, float* __restrict__ out_rs,
           float* __restrict__ out_old, float* __restrict__ out_nsel) {
    const int b = blockIdx.x, tid = threadIdx.x;
    const int w = tid >> 6, lane = tid & 63;
    const int RPB = CPB * BS;
    const int Rb = b * RPB;
    const int Lact = min(RPB, N - Rb);

    __shared__ u64 smask[CPB * 4];
    __shared__ int chunkcnt[CPB];
    __shared__ int shBase, shTot;

    if (tid < CPB * 4) smask[tid] = gmask[(long)b * CPB * 4 + tid];

    // exclusive prefix of cnts up to b + grand total (redundant, L2-hot)
    if (tid < 64) {
        int pre = 0, tot = 0;
        for (int k = tid; k < G2; k += 64) {
            int c = cnts[k];
            tot += c;
            pre += (k < b) ? c : 0;
        }
        for (int d = 32; d > 0; d >>= 1) {
            pre += __shfl_down(pre, d);
            tot += __shfl_down(tot, d);
        }
        if (tid == 0) { shBase = pre; shTot = tot; }
    }
    __syncthreads();
    if (tid < CPB) {
        const u64* mw = &smask[tid * 4];
        chunkcnt[tid] = __popcll(mw[0]) + __popcll(mw[1]) + __popcll(mw[2]) + __popcll(mw[3]);
    }
    __syncthreads();
    const int myBase = shBase, total = shTot;

    if (b == 0 && tid == 0) { out_nsel[0] = (float)total; out_old[0] = (float)N; }

    // write selected row indices (final float values) at compacted positions
    {
        int basec = 0;
        for (int c = 0; c < CPB; ++c) {
            u64 mybal = smask[c * 4 + w];
            int wb = 0;
            for (int k = 0; k < w; ++k) wb += __popcll(smask[c * 4 + k]);
            if ((mybal >> (unsigned)lane) & 1ULL) {
                int rank = basec + wb + __popcll(mybal & ((1ULL << (unsigned)lane) - 1ULL));
                out_idx[(long)myBase + rank] = (float)(Rb + c * BS + tid);
            }
            basec += chunkcnt[c];
        }
    }

    // new_rs boundaries owned by this block (pos>=N -> last block)
    for (int s = tid; s <= B; s += BS) {
        int pos = rsp[s];
        if (pos >= Rb && pos < Rb + Lact) {
            int rel = pos - Rb;
            int nw = rel >> 6, rem = rel & 63;
            int cnt = 0;
            for (int k = 0; k < nw; ++k) cnt += __popcll(smask[k]);
            if (rem) cnt += __popcll(smask[nw] & ((1ULL << (unsigned)rem) - 1ULL));
            out_rs[s] = (float)(myBase + cnt);
        } else if (b == G2 - 1 && pos >= N) {
            out_rs[s] = (float)total;
        }
    }
}

// ---------------- Node 4: fill-shaped forward writer -----------------------
// Grid-stride over 32-row output groups; contiguous stores everywhere.
__global__ __launch_bounds__(BS)
void k_write(const float* __restrict__ x, const int* __restrict__ ws_total,
             int N, int F, float* __restrict__ out_x, float* __restrict__ out_idx) {
    const int total = *ws_total;
    const int tid = threadIdx.x;
    const int Fv = F >> 2;
    if ((F & 3) == 0 && Fv > 0 && (BS % Fv) == 0) {
        const int rpg = BS / Fv;                 // rows per group (32 for F=32)
        const int ngroups = (N + rpg - 1) / rpg;
        const f32x4* x4 = (const f32x4*)x;
        f32x4* o4 = (f32x4*)out_x;
        const int rr = tid / Fv, cc = tid - (tid / Fv) * Fv;
        for (int g = blockIdx.x; g < ngroups; g += gridDim.x) {
            int row = g * rpg + rr;
            if (row >= N) continue;
            if (row < total) {
                int src = (int)out_idx[row];     // written by k_sel (exact float)
                o4[(long)row * Fv + cc] = x4[(long)src * Fv + cc];
            } else {
                o4[(long)row * Fv + cc] = (f32x4)(0.0f);
                if (cc == 0) out_idx[row] = -1.0f;
            }
        }
    } else {
        // scalar fallback: one row per thread (read idx once, then elements)
        for (int row = blockIdx.x * BS + tid; row < N; row += gridDim.x * BS) {
            if (row < total) {
                int src = (int)out_idx[row];
                for (int c = 0; c < F; ++c)
                    out_x[(long)row * F + c] = x[(long)src * F + c];
            } else {
                for (int c = 0; c < F; ++c) out_x[(long)row * F + c] = 0.0f;
                out_idx[row] = -1.0f;
            }
        }
    }
}

extern "C" void kernel_launch(void* const* d_in, const int* in_sizes, int n_in,
                              void* d_out, int out_size, void* d_ws, size_t ws_size,
                              hipStream_t stream) {
    const float* x     = (const float*)d_in[0];
    const float* score = (const float*)d_in[1];
    const int*   track = (const int*)d_in[2];
    const int*   rs    = (const int*)d_in[3];

    int N = in_sizes[1];            // rows
    int F = in_sizes[0] / N;        // 32
    int B = in_sizes[3] - 1;        // 64

    int nchunks = (N + BS - 1) / BS;
    int G2 = (nchunks + CPB - 1) / CPB;

    int SPS = B > 0 ? (1024 / B) : 1;
    if (SPS < 1) SPS = 1;
    if (SPS > 64) SPS = 64;
    int G1 = B * SPS;

    // workspace layout
    float* part_min = (float*)d_ws;                 // G1 floats
    int*   ws_total = (int*)(part_min + G1);        // 1 int
    int*   cnts     = ws_total + 1;                 // G2 ints
    u64*   gmask    = (u64*)(((uintptr_t)(cnts + G2) + 15) & ~(uintptr_t)15); // G2*CPB*4

    // output layout (all float32 values)
    float* out      = (float*)d_out;
    long off_rs   = (long)N * F;
    long off_old  = off_rs + (B + 1);
    long off_idx  = off_old + 1;
    long off_nsel = off_idx + N;

    float* out_x    = out;
    float* out_rs   = out + off_rs;
    float* out_old  = out + off_old;
    float* out_idx  = out + off_idx;
    float* out_nsel = out + off_nsel;

    // grid for k_write
    int Fv = F >> 2;
    int GW;
    if ((F & 3) == 0 && Fv > 0 && (BS % Fv) == 0) {
        int rpg = BS / Fv;
        int ngroups = (N + rpg - 1) / rpg;
        GW = ngroups < 2048 ? ngroups : 2048;
    } else {
        GW = ((N + BS - 1) / BS) < 2048 ? ((N + BS - 1) / BS) : 2048;
    }
    if (GW < 1) GW = 1;

    k_segmin<<<G1, BS, 0, stream>>>(score, track, rs, B, SPS, part_min, ws_total);
    k_count<<<G2, BS, 0, stream>>>(score, track, part_min, N, B, SPS, gmask, cnts, ws_total);
    k_sel<<<G2, BS, 0, stream>>>(rs, gmask, cnts, N, B, G2, out_idx, out_rs, out_old, out_nsel);
    k_write<<<GW, BS, 0, stream>>>(x, ws_total, N, F, out_x, out_idx);
}

// Round 12
// 78.447 us; speedup vs baseline: 1.3084x; 1.3084x over previous
//
#include <hip/hip_runtime.h>
#include <stdint.h>

#define BS 256
#define CPB 4          // chunks (of BS rows) per count/main block
#define NW 16          // mask words per block (CPB * 4)
#define PF 8           // gather prefetch depth (f32x4 registers)

typedef unsigned long long u64;
typedef float f32x4 __attribute__((ext_vector_type(4)));

// ---------------- Node 1: per-(segment,slot) partial min --------------------
__global__ __launch_bounds__(BS)
void k_segmin(const float* __restrict__ score, const int* __restrict__ track,
              const int* __restrict__ rs, int B, int SPS,
              float* __restrict__ part_min) {
    int b = blockIdx.x;
    int s = b / SPS, j = b - s * SPS;
    int r0 = rs[s], r1 = rs[s + 1];
    int len = r1 - r0;
    int per = (len + SPS - 1) / SPS;
    int a = r0 + j * per;
    int e = min(r1, a + per);
    float m = INFINITY;
    for (int i = a + (int)threadIdx.x; i < e; i += BS)
        m = fminf(m, track[i] ? 0.0f : score[i]);
    for (int d = 32; d > 0; d >>= 1) m = fminf(m, __shfl_down(m, d));
    __shared__ float wmin[BS / 64];
    if ((threadIdx.x & 63) == 0) wmin[threadIdx.x >> 6] = m;
    __syncthreads();
    if (threadIdx.x == 0) {
        float mm = wmin[0];
        for (int k = 1; k < BS / 64; ++k) mm = fminf(mm, wmin[k]);
        part_min[b] = mm;
    }
}

// ---------------- Node 2: threshold + ballots -> masks + counts -------------
__global__ __launch_bounds__(BS)
void k_count(const float* __restrict__ score, const int* __restrict__ track,
             const float* __restrict__ part_min, int N, int B, int SPS,
             u64* __restrict__ gmask, int* __restrict__ cnts) {
    const int b = blockIdx.x, tid = threadIdx.x;
    const int w = tid >> 6, lane = tid & 63;
    __shared__ float shT;
    __shared__ u64 smask[NW];

    if (tid < 64) {
        float m = -INFINITY;
        for (int s = tid; s < B; s += 64) {
            float mn = INFINITY;
            for (int j = 0; j < SPS; ++j) mn = fminf(mn, part_min[s * SPS + j]);
            m = fmaxf(m, mn);
        }
        for (int d = 32; d > 0; d >>= 1) m = fmaxf(m, __shfl_xor(m, d));
        if (tid == 0) shT = (m < 0.1f) ? 0.1f : (m + 1e-7f);
    }
    __syncthreads();
    const float T = shT;

    const long Rb = (long)b * CPB * BS;
    for (int c = 0; c < CPB; ++c) {
        long i = Rb + (long)c * BS + tid;
        bool pred = (i < N) && ((track[i] ? 0.0f : score[i]) <= T);
        u64 bal = __ballot(pred);
        if (lane == 0) smask[c * 4 + w] = bal;
    }
    __syncthreads();
    if (tid < NW) gmask[(long)b * NW + tid] = smask[tid];
    if (tid == 0) {
        int c = 0;
        for (int k = 0; k < NW; ++k) c += __popcll(smask[k]);
        cnts[b] = c;
    }
}

// ---------------- Node 3: fused prefix + build + prefetched copy + zero -----
__global__ __launch_bounds__(BS)
void k_main(const float* __restrict__ x, const int* __restrict__ rsp,
            const u64* __restrict__ gmask, const int* __restrict__ cnts,
            int N, int B, int F, int G2,
            float* __restrict__ out_x, float* __restrict__ out_rs,
            float* __restrict__ out_old, float* __restrict__ out_idx,
            float* __restrict__ out_nsel) {
    const int b = blockIdx.x, tid = threadIdx.x;
    const int w = tid >> 6, lane = tid & 63;
    const int RPB = CPB * BS;
    const int Rb = b * RPB;
    const int Lact = min(RPB, N - Rb);

    __shared__ u64 smask[NW];
    __shared__ int rows[RPB];
    __shared__ int shPre[BS / 64], shTot4[BS / 64];

    if (tid < NW) smask[tid] = gmask[(long)b * NW + tid];

    // ---- all-thread prefix over cnts[0..G2) ----
    int pre = 0, tot = 0;
    for (int k = tid; k < G2; k += BS) {
        int c = cnts[k];
        tot += c;
        pre += (k < b) ? c : 0;
    }
    for (int d = 32; d > 0; d >>= 1) {
        pre += __shfl_down(pre, d);
        tot += __shfl_down(tot, d);
    }
    if (lane == 0) { shPre[w] = pre; shTot4[w] = tot; }
    __syncthreads();                       // barrier 1: smask + prefix partials
    int myBase = 0, total = 0;
#pragma unroll
    for (int k = 0; k < BS / 64; ++k) { myBase += shPre[k]; total += shTot4[k]; }

    if (b == 0 && tid == 0) { out_nsel[0] = (float)total; out_old[0] = (float)N; }

    // ---- per-thread popcounts (static, registers) ----
    int p[NW];
#pragma unroll
    for (int j = 0; j < NW; ++j) p[j] = __popcll(smask[j]);
    int bcnt = 0;
#pragma unroll
    for (int j = 0; j < NW; ++j) bcnt += p[j];

    // ---- build row list (all chunks, no intervening barriers) + idx writes ----
#pragma unroll
    for (int c = 0; c < CPB; ++c) {
        u64 mybal = smask[c * 4 + w];
        if ((mybal >> (unsigned)lane) & 1ULL) {
            int basew = 0;
#pragma unroll
            for (int j = 0; j < NW; ++j) basew += (j < c * 4 + w) ? p[j] : 0;
            int rank = basew + __popcll(mybal & ((1ULL << (unsigned)lane) - 1ULL));
            int row = Rb + c * BS + tid;
            rows[rank] = row;
            out_idx[(long)myBase + rank] = (float)row;
        }
    }
    __syncthreads();                       // barrier 2: rows ready

    const int Fv = F >> 2;
    const bool vec = ((F & 3) == 0) && (Fv > 0) && (BS % Fv == 0);

    const int unsel = Lact - bcnt;
    const long Unext = (long)(Rb + Lact) - (long)(myBase + bcnt);
    const long zr0 = (long)N - Unext;      // this block's zero-tail row start

    if (vec) {
        const f32x4* x4 = (const f32x4*)x;
        f32x4* o4 = (f32x4*)out_x;
        const int rstep = BS / Fv;
        const int r0 = tid / Fv, cc = tid - (tid / Fv) * Fv;

        // ---- phase A: issue guarded gather loads (fill MLP) ----
        f32x4 v0, v1, v2, v3, v4, v5, v6, v7;
        const int q0 = r0,             q1 = r0 + rstep,     q2 = r0 + 2 * rstep,
                  q3 = r0 + 3 * rstep, q4 = r0 + 4 * rstep, q5 = r0 + 5 * rstep,
                  q6 = r0 + 6 * rstep, q7 = r0 + 7 * rstep;
        if (q0 < bcnt) v0 = x4[(long)rows[q0] * Fv + cc];
        if (q1 < bcnt) v1 = x4[(long)rows[q1] * Fv + cc];
        if (q2 < bcnt) v2 = x4[(long)rows[q2] * Fv + cc];
        if (q3 < bcnt) v3 = x4[(long)rows[q3] * Fv + cc];
        if (q4 < bcnt) v4 = x4[(long)rows[q4] * Fv + cc];
        if (q5 < bcnt) v5 = x4[(long)rows[q5] * Fv + cc];
        if (q6 < bcnt) v6 = x4[(long)rows[q6] * Fv + cc];
        if (q7 < bcnt) v7 = x4[(long)rows[q7] * Fv + cc];

        // ---- phase B: streaming zero stores (independent; hides load latency) ----
        {
            f32x4 z = (f32x4)(0.0f);
            f32x4* zb = o4 + zr0 * Fv;
            const int ecnt = unsel * Fv;
            for (int e = tid; e < ecnt; e += BS) zb[e] = z;
        }
        for (int t = tid; t < unsel; t += BS) out_idx[zr0 + t] = -1.0f;

        // ---- phase C: gathered stores ----
        f32x4* ob = o4 + (long)myBase * Fv;
        if (q0 < bcnt) ob[(long)q0 * Fv + cc] = v0;
        if (q1 < bcnt) ob[(long)q1 * Fv + cc] = v1;
        if (q2 < bcnt) ob[(long)q2 * Fv + cc] = v2;
        if (q3 < bcnt) ob[(long)q3 * Fv + cc] = v3;
        if (q4 < bcnt) ob[(long)q4 * Fv + cc] = v4;
        if (q5 < bcnt) ob[(long)q5 * Fv + cc] = v5;
        if (q6 < bcnt) ob[(long)q6 * Fv + cc] = v6;
        if (q7 < bcnt) ob[(long)q7 * Fv + cc] = v7;

        // ---- residual (dense blocks only) ----
        for (int r = r0 + PF * rstep; r < bcnt; r += rstep)
            ob[(long)r * Fv + cc] = x4[(long)rows[r] * Fv + cc];
    } else {
        // scalar fallback
        for (int e = tid; e < bcnt * F; e += BS) {
            int r = e / F, cc2 = e - r * F;
            out_x[((long)myBase + r) * F + cc2] = x[(long)rows[r] * F + cc2];
        }
        long e0 = zr0 * (long)F, ecnt = (long)unsel * F;
        for (long e = tid; e < ecnt; e += BS) out_x[e0 + e] = 0.0f;
        for (int t = tid; t < unsel; t += BS) out_idx[zr0 + t] = -1.0f;
    }

    // ---- new_rs boundaries owned by this block (pos>=N -> last block) ----
    for (int s = tid; s <= B; s += BS) {
        int pos = rsp[s];
        if (pos >= Rb && pos < Rb + Lact) {
            int rel = pos - Rb;
            int nw2 = rel >> 6, rem = rel & 63;
            int cnt = 0;
            for (int k = 0; k < nw2; ++k) cnt += __popcll(smask[k]);
            if (rem) cnt += __popcll(smask[nw2] & ((1ULL << (unsigned)rem) - 1ULL));
            out_rs[s] = (float)(myBase + cnt);
        } else if (b == G2 - 1 && pos >= N) {
            out_rs[s] = (float)total;
        }
    }
}

extern "C" void kernel_launch(void* const* d_in, const int* in_sizes, int n_in,
                              void* d_out, int out_size, void* d_ws, size_t ws_size,
                              hipStream_t stream) {
    const float* x     = (const float*)d_in[0];
    const float* score = (const float*)d_in[1];
    const int*   track = (const int*)d_in[2];
    const int*   rs    = (const int*)d_in[3];

    int N = in_sizes[1];            // rows
    int F = in_sizes[0] / N;        // 32
    int B = in_sizes[3] - 1;        // 64

    int nchunks = (N + BS - 1) / BS;
    int G2 = (nchunks + CPB - 1) / CPB;

    int SPS = B > 0 ? (1024 / B) : 1;
    if (SPS < 1) SPS = 1;
    if (SPS > 64) SPS = 64;
    int G1 = B * SPS;

    // workspace layout
    float* part_min = (float*)d_ws;                 // G1 floats
    int*   cnts     = (int*)(part_min + G1);        // G2 ints
    u64*   gmask    = (u64*)(((uintptr_t)(cnts + G2) + 15) & ~(uintptr_t)15); // G2*NW

    // output layout (all float32 values)
    float* out      = (float*)d_out;
    long off_rs   = (long)N * F;
    long off_old  = off_rs + (B + 1);
    long off_idx  = off_old + 1;
    long off_nsel = off_idx + N;

    float* out_x    = out;
    float* out_rs   = out + off_rs;
    float* out_old  = out + off_old;
    float* out_idx  = out + off_idx;
    float* out_nsel = out + off_nsel;

    k_segmin<<<G1, BS, 0, stream>>>(score, track, rs, B, SPS, part_min);
    k_count<<<G2, BS, 0, stream>>>(score, track, part_min, N, B, SPS, gmask, cnts);
    k_main<<<G2, BS, 0, stream>>>(x, rs, gmask, cnts, N, B, F, G2,
                                  out_x, out_rs, out_old, out_idx, out_nsel);
}